// Round 10
// baseline (315.885 us; speedup 1.0000x reference)
//
#include <hip/hip_runtime.h>

// ---------- types / helpers ----------
typedef __bf16 bf16x8 __attribute__((ext_vector_type(8)));
typedef float f32x4 __attribute__((ext_vector_type(4)));
typedef float f32x16 __attribute__((ext_vector_type(16)));

struct alignas(16) US8 { unsigned short us[8]; };

static __device__ inline unsigned short f2bf(float f) {
  union { float f; unsigned u; } v; v.f = f;
  unsigned r = v.u + 0x7fffu + ((v.u >> 16) & 1u);   // RNE
  return (unsigned short)(r >> 16);
}

static __device__ inline void gload16(const unsigned short* g, unsigned short* l) {
  // direct-to-LDS DMA, 16B/lane; LDS dest = wave-uniform base + lane*16
  __builtin_amdgcn_global_load_lds(
      (const __attribute__((address_space(1))) void*)g,
      (__attribute__((address_space(3))) void*)l, 16, 0, 0);
}

// B=8, N=4096, D=128.  32768 total rows.
#define NSEQ 4096
#define DIM 128
#define ROWS 32768
#define KH 4                      // cross-block key splits in attn
#define NBLK 512                  // attn grid; ALL co-resident (2 blocks/CU guaranteed by
                                  // launch_bounds(256,2) + 64KB LDS) -> manual grid barrier ok

// log2(e)/sqrt(128): folded into q so S exits QK^T already in log2 domain
#define EXPC (1.4426950408889634f * 0.08838834764831845f)

// ---------- kv GEMM (blocks 0..1023) + qcast tail (blocks 1024..3071), ONE launch ----------
// prep_kernel is GONE: each GEMM block transposes its fp32 Wkv col-half directly into LDS
// (same f2bf bits as the old prep + stage; Wkv is 131 KB, L2-resident).
// GEMM: COLUMN-SPLIT, 512 row-groups x 2 col-halves (34.8 KB LDS -> 4 blocks/CU).
// half 0 -> k (LDS restage, coalesced uint4 row-major stores);
// half 1 -> v (LDS transpose, blocked+permuted).
// Blocked V layout per batch: [tile(64 keys)][chunk 16][lane 64][8] where chunk=(mg,dh):
//   element (chunk, l, j) = V[m' = mg*8+j][d = dh*64+l], m' = key order with bit2<->bit3
//   swapped per 16-block (matches 32x32 MFMA C/D->A reg order in attn's PV).
// Blocked q_hat layout per batch: [tile(64 rows)][kc 16][lane 64][8]:
//   element = q_hat[row = tile*64+l][d = kc*8+j].
__global__ __launch_bounds__(256, 4) void kvq_kernel(
    const float* __restrict__ x, const float* __restrict__ Wkv,
    const float* __restrict__ bkv, const float* __restrict__ q,
    unsigned short* __restrict__ kout, unsigned short* __restrict__ vtout,
    unsigned short* __restrict__ qo, int* cnt) {
  const int tid = threadIdx.x;
  if (blockIdx.x == 0 && tid == 0) *cnt = 0;   // reset fused-attn grid-barrier counter
  __shared__ __align__(16) unsigned short WT[128 * 136];   // [col][d] stride 136 (34.8 KB)
  if (blockIdx.x >= 1024) {                 // qcast tail -> blocked layout
    int i = ((blockIdx.x - 1024) * 256 + tid) * 8;
    const float4* p = reinterpret_cast<const float4*>(q + i);
    float4 a = p[0], b = p[1];
    US8 o;
    o.us[0]=f2bf(a.x*EXPC); o.us[1]=f2bf(a.y*EXPC); o.us[2]=f2bf(a.z*EXPC); o.us[3]=f2bf(a.w*EXPC);
    o.us[4]=f2bf(b.x*EXPC); o.us[5]=f2bf(b.y*EXPC); o.us[6]=f2bf(b.z*EXPC); o.us[7]=f2bf(b.w*EXPC);
    int row = i >> 7, d0 = i & 127;
    int bb = row >> 12, n = row & (NSEQ - 1), tile = n >> 6, l = n & 63, kc = d0 >> 3;
    *reinterpret_cast<US8*>(qo + (size_t)bb * NSEQ * DIM + tile * 8192 + kc * 512 + l * 8) = o;
    return;
  }
  const int wv = tid >> 6, lane = tid & 63, l16 = lane & 15, quad = lane >> 4;
  const int half = blockIdx.x & 1;
  const int row0 = (blockIdx.x >> 1) * 64;

  // stage: transpose this fp32 Wkv col-half (coalesced float2 reads, once per block)
  for (int p = 0; p < 32; ++p) {
    int c = p * 256 + tid;
    int col0 = (c & 63) * 2, d = c >> 6;
    float2 w = *reinterpret_cast<const float2*>(Wkv + d * 256 + half * 128 + col0);
    WT[col0 * 136 + d] = f2bf(w.x);
    WT[(col0 + 1) * 136 + d] = f2bf(w.y);
  }
  __syncthreads();

  bf16x8 afrag[4];
  const int arow = row0 + wv * 16 + l16;
  for (int s = 0; s < 4; ++s) {
    const float4* xp = reinterpret_cast<const float4*>(x + (size_t)arow * DIM + s * 32 + quad * 8);
    float4 u0 = xp[0], u1 = xp[1];
    US8 af;
    af.us[0]=f2bf(u0.x); af.us[1]=f2bf(u0.y); af.us[2]=f2bf(u0.z); af.us[3]=f2bf(u0.w);
    af.us[4]=f2bf(u1.x); af.us[5]=f2bf(u1.y); af.us[6]=f2bf(u1.z); af.us[7]=f2bf(u1.w);
    afrag[s] = __builtin_bit_cast(bf16x8, af);
  }
  f32x4 acc[8];
  for (int g = 0; g < 8; ++g) acc[g] = f32x4{0.f, 0.f, 0.f, 0.f};
  for (int s = 0; s < 4; ++s)
    for (int g = 0; g < 8; ++g) {
      bf16x8 bfr = *reinterpret_cast<const bf16x8*>(&WT[(g * 16 + l16) * 136 + s * 32 + quad * 8]);
      acc[g] = __builtin_amdgcn_mfma_f32_16x16x32_bf16(afrag[s], bfr, acc[g], 0, 0, 0);
    }

  __syncthreads();                          // all waves done reading weights from WT
  if (half == 0) {
    // k: stage rows into LDS [rowl][col] stride 136, then coalesced b128 row-major stores.
    // C/D: row=quad*4+r, col=l16
    for (int g = 0; g < 8; ++g) {
      float bias = bkv[g * 16 + l16];
      for (int r = 0; r < 4; ++r)
        WT[(wv * 16 + quad * 4 + r) * 136 + g * 16 + l16] = f2bf(acc[g][r] + bias);
    }
    __syncthreads();
    unsigned short* kbo = kout + (size_t)row0 * DIM;
    for (int p = 0; p < 4; ++p) {           // 1024 16B units: 64 rows x 16 segs
      int c = p * 256 + tid;
      int rowl = c >> 4, seg = c & 15;
      *reinterpret_cast<uint4*>(kbo + (size_t)rowl * DIM + seg * 8) =
          *reinterpret_cast<const uint4*>(&WT[rowl * 136 + seg * 8]);
    }
  } else {
    // v: transpose through LDS (stride 72), then blocked+permuted b128 global stores
    unsigned short* LDSt = WT;              // [d 128][n_local 64] stride 72 (reuses WT)
    for (int g = 0; g < 8; ++g) {
      float bias = bkv[128 + g * 16 + l16];
      for (int r = 0; r < 4; ++r)
        LDSt[(g * 16 + l16) * 72 + wv * 16 + quad * 4 + r] = f2bf(acc[g][r] + bias);
    }
    __syncthreads();
    const int bb = row0 >> 12;
    const int tile = (row0 & (NSEQ - 1)) >> 6;
    unsigned short* vbo = vtout + (size_t)bb * NSEQ * DIM + (size_t)tile * 8192;
    for (int p = 0; p < 4; ++p) {           // 1024 16B units: 16 chunks x 64 lanes
      int c = p * 256 + tid;
      int idx = c >> 6, l = c & 63;
      int mg = idx >> 1, dh = idx & 1, d = dh * 64 + l;
      int nb = (mg >> 1) * 16 + (mg & 1) * 4;   // first 4-run (bit2<->3 swap)
      uint2 lo = *reinterpret_cast<const uint2*>(&LDSt[d * 72 + nb]);
      uint2 hi = *reinterpret_cast<const uint2*>(&LDSt[d * 72 + nb + 8]);
      uint4 o{lo.x, lo.y, hi.x, hi.y};
      *reinterpret_cast<uint4*>(vbo + (size_t)idx * 512 + l * 8) = o;
    }
  }
}

// ---------- fused attention + combine/projection (manual grid barrier) ----------
// Phase 1: flash attention partials, grid 512 = 8 batches x 16 q-tiles (256 rows) x 4 key-
// splits; 2 blocks/CU, 64 KB LDS dbuf; 64 n-rows/wave, 2-PASS QK with SPLIT-K accumulation
// (Se over even ks, So over odd): two interleaved 4-long dependent MFMA chains instead of
// one 8-long chain -> better matrix-pipe fill.  VGPR peak during QK: kfrag 64 + Se/So 32 +
// operands ~20 < 128 (vs r5's 132+ which spilled).  O partials written bf16.
// Grid barrier: all 512 blocks co-resident (2/CU exact); threadfence + atomicAdd + spin.
// Phase 2: each block combines KH slices of 64 rows, projects through Wp (staged fp32->bf16
// into reused SH), writes out.  prep/combine kernels are gone (4 launches -> 2).
__global__ __launch_bounds__(256, 2) void attn_kernel(
    const unsigned short* __restrict__ kbuf, const unsigned short* __restrict__ qblk,
    const unsigned short* __restrict__ vblk,
    unsigned short* __restrict__ opart, float* __restrict__ lpart,
    const float* __restrict__ Wp, const float* __restrict__ bp,
    float* __restrict__ out, int* cnt) {
  __shared__ __align__(16) unsigned short SH[32768];   // 2 x (Qh 8192 | V 8192) = 64 KB
  const int tid = threadIdx.x;
  const int wv = tid >> 6, lane = tid & 63, l32 = lane & 31, h = lane >> 5;
  const int b = blockIdx.x & 7;
  const int t = blockIdx.x >> 3;
  const int q0 = (t & 15) * 256;
  const int kh = t >> 4;                    // 0..3
  const int key0 = kh * (NSEQ / KH);
  const unsigned short* kb = kbuf + (size_t)b * NSEQ * DIM;
  const unsigned short* qb = qblk + (size_t)b * NSEQ * DIM;
  const unsigned short* vb = vblk + (size_t)b * NSEQ * DIM;

  // staging: waves 0-1 stage the 16 q-hat chunks, waves 2-3 the 16 V chunks
  const unsigned short* sbase = ((wv < 2) ? qb : vb) + (size_t)(key0 >> 6) * 8192
                                + (wv & 1) * 4096 + lane * 8;
  const int ldst = (wv >> 1) * 8192 + (wv & 1) * 4096;   // us offset within a buffer

  constexpr int NT = NSEQ / KH / 64;        // 16

  // prologue: stage tile 0 into buffer 0 (overlaps kfrag loads)
#pragma unroll
  for (int c = 0; c < 8; ++c)
    gload16(sbase + c * 512, &SH[ldst + c * 512]);

  // B-operand frags: this wave's 64 n-rows of k (2 sets of 32). B[k=h*8+j][n=l32]
  bf16x8 kfrag[2][8];
#pragma unroll
  for (int nf = 0; nf < 2; ++nf)
#pragma unroll
    for (int ks = 0; ks < 8; ++ks)
      kfrag[nf][ks] = __builtin_bit_cast(bf16x8, *reinterpret_cast<const US8*>(
          kb + (size_t)(q0 + nf * 128 + wv * 32 + l32) * DIM + ks * 16 + h * 8));

  f32x16 Oacc[2][4];
#pragma unroll
  for (int nf = 0; nf < 2; ++nf)
    for (int dt = 0; dt < 4; ++dt)
      for (int i = 0; i < 16; ++i) Oacc[nf][dt][i] = 0.f;
  float lsum0 = 0.f, lsum1 = 0.f;

  __syncthreads();                          // tile 0 staged (vmcnt(0) + barrier)

  for (int it = 0; it < NT; ++it) {
    const int cur = (it & 1) << 14;         // 0 / 16384
    if (it + 1 < NT) {                      // issue next tile's DMA into other buffer
      const int nxt = cur ^ 16384;
      const unsigned short* sp = sbase + (size_t)(it + 1) * 8192;
#pragma unroll
      for (int c = 0; c < 8; ++c)
        gload16(sp + c * 512, &SH[nxt + ldst + c * 512]);
    }
    const unsigned short* Qsh = SH + cur;
    const unsigned short* Vsh = Qsh + 8192;

#pragma unroll
    for (int T = 0; T < 2; ++T) {
      bf16x8 pA[2], pB[2];
      // ---- QK pass 1 (n-set 0), split-K: Se (even ks) / So (odd ks) interleaved ----
      {
        f32x16 Se, So;
        for (int i = 0; i < 16; ++i) { Se[i] = 0.f; So[i] = 0.f; }
        __builtin_amdgcn_s_setprio(1);
#pragma unroll
        for (int ks = 0; ks < 8; ks += 2) {
          bf16x8 a0 = *reinterpret_cast<const bf16x8*>(
              &Qsh[(ks * 2 + h) * 512 + (T * 32 + l32) * 8]);
          bf16x8 a1 = *reinterpret_cast<const bf16x8*>(
              &Qsh[((ks + 1) * 2 + h) * 512 + (T * 32 + l32) * 8]);
          Se = __builtin_amdgcn_mfma_f32_32x32x16_bf16(a0, kfrag[0][ks], Se, 0, 0, 0);
          So = __builtin_amdgcn_mfma_f32_32x32x16_bf16(a1, kfrag[0][ks + 1], So, 0, 0, 0);
        }
        __builtin_amdgcn_s_setprio(0);
#pragma unroll
        for (int i = 0; i < 16; ++i) Se[i] += So[i];
        unsigned pk[8];
#pragma unroll
        for (int i2 = 0; i2 < 8; ++i2) {
          float e0 = __builtin_amdgcn_exp2f(Se[i2 * 2]);
          float e1 = __builtin_amdgcn_exp2f(Se[i2 * 2 + 1]);
          lsum0 += e0; lsum0 += e1;
          pk[i2] = __builtin_amdgcn_perm(__builtin_bit_cast(unsigned, e1),
                                         __builtin_bit_cast(unsigned, e0), 0x07060302u);
        }
        pA[0] = __builtin_bit_cast(bf16x8, uint4{pk[0], pk[1], pk[2], pk[3]});
        pA[1] = __builtin_bit_cast(bf16x8, uint4{pk[4], pk[5], pk[6], pk[7]});
      }
      // ---- QK pass 2 (n-set 1), split-K, same q-hat chunks re-read ----
      {
        f32x16 Se, So;
        for (int i = 0; i < 16; ++i) { Se[i] = 0.f; So[i] = 0.f; }
        __builtin_amdgcn_s_setprio(1);
#pragma unroll
        for (int ks = 0; ks < 8; ks += 2) {
          bf16x8 a0 = *reinterpret_cast<const bf16x8*>(
              &Qsh[(ks * 2 + h) * 512 + (T * 32 + l32) * 8]);
          bf16x8 a1 = *reinterpret_cast<const bf16x8*>(
              &Qsh[((ks + 1) * 2 + h) * 512 + (T * 32 + l32) * 8]);
          Se = __builtin_amdgcn_mfma_f32_32x32x16_bf16(a0, kfrag[1][ks], Se, 0, 0, 0);
          So = __builtin_amdgcn_mfma_f32_32x32x16_bf16(a1, kfrag[1][ks + 1], So, 0, 0, 0);
        }
        __builtin_amdgcn_s_setprio(0);
#pragma unroll
        for (int i = 0; i < 16; ++i) Se[i] += So[i];
        unsigned pk[8];
#pragma unroll
        for (int i2 = 0; i2 < 8; ++i2) {
          float e0 = __builtin_amdgcn_exp2f(Se[i2 * 2]);
          float e1 = __builtin_amdgcn_exp2f(Se[i2 * 2 + 1]);
          lsum1 += e0; lsum1 += e1;
          pk[i2] = __builtin_amdgcn_perm(__builtin_bit_cast(unsigned, e1),
                                         __builtin_bit_cast(unsigned, e0), 0x07060302u);
        }
        pB[0] = __builtin_bit_cast(bf16x8, uint4{pk[0], pk[1], pk[2], pk[3]});
        pB[1] = __builtin_bit_cast(bf16x8, uint4{pk[4], pk[5], pk[6], pk[7]});
      }
      // ---- PV for m-tile T: each V read feeds 2 MFMAs (both n-sets) ----
      __builtin_amdgcn_s_setprio(1);
#pragma unroll
      for (int s = 0; s < 2; ++s) {
        const int mg = 4 * T + 2 * s + h;
#pragma unroll
        for (int dt = 0; dt < 4; ++dt) {
          bf16x8 bv = *reinterpret_cast<const bf16x8*>(
              &Vsh[(mg * 2 + (dt >> 1)) * 512 + ((dt & 1) * 32 + l32) * 8]);
          Oacc[0][dt] = __builtin_amdgcn_mfma_f32_32x32x16_bf16(pA[s], bv, Oacc[0][dt], 0, 0, 0);
          Oacc[1][dt] = __builtin_amdgcn_mfma_f32_32x32x16_bf16(pB[s], bv, Oacc[1][dt], 0, 0, 0);
        }
      }
      __builtin_amdgcn_s_setprio(0);
    }

    __syncthreads();   // reads of buf[cur] done; next tile's DMA drained (vmcnt(0))
  }

  // l: per-lane covers its h-half of m for q-row n=l32 of each n-set; merge halves
  {
    float v0 = lsum0 + __shfl_xor(lsum0, 32);
    float v1 = lsum1 + __shfl_xor(lsum1, 32);
    if (lane < 32) {
      lpart[(size_t)kh * ROWS + (size_t)b * NSEQ + q0 + wv * 32 + l32] = v0;
      lpart[(size_t)kh * ROWS + (size_t)b * NSEQ + q0 + 128 + wv * 32 + l32] = v1;
    }
  }
#pragma unroll
  for (int nf = 0; nf < 2; ++nf) {
    unsigned short* ob = opart + (size_t)kh * ROWS * DIM
                         + ((size_t)b * NSEQ + q0 + nf * 128 + wv * 32) * DIM;
    for (int dt = 0; dt < 4; ++dt)
      for (int i = 0; i < 16; ++i) {
        int n = (i & 3) + 8 * (i >> 2) + 4 * h;   // 32x32 C/D row map (measured m74/m101)
        ob[n * DIM + dt * 32 + l32] = f2bf(Oacc[nf][dt][i]);
      }
  }

  // ---- grid barrier: every thread fences its stores, then one thread signals+spins ----
  __threadfence();
  __syncthreads();
  if (tid == 0) {
    atomicAdd(cnt, 1);
    while (__hip_atomic_load(cnt, __ATOMIC_ACQUIRE, __HIP_MEMORY_SCOPE_AGENT) < NBLK)
      __builtin_amdgcn_s_sleep(2);
    __threadfence();
  }
  __syncthreads();

  // ---- phase 2: combine KH bf16 partial slices, normalize, out = o @ Wp + bp ----
  {
    unsigned short* WT = SH;                // reuse LDS: [col][d] stride 136 (34.8 KB)
    for (int p = 0; p < 32; ++p) {          // transpose fp32 Wp -> bf16 (coalesced float2)
      int c = p * 256 + tid;
      int col0 = (c & 63) * 2, d = c >> 6;
      float2 w = *reinterpret_cast<const float2*>(Wp + d * 128 + col0);
      WT[col0 * 136 + d] = f2bf(w.x);
      WT[(col0 + 1) * 136 + d] = f2bf(w.y);
    }
    __syncthreads();

    const int l16 = lane & 15, quad = lane >> 4;
    const int row0c = (int)blockIdx.x * 64;
    f32x4 acc[8];
    for (int g = 0; g < 8; ++g) acc[g] = f32x4{0.f, 0.f, 0.f, 0.f};
    const int arow = row0c + wv * 16 + l16;
    float lsum = 0.f;
#pragma unroll
    for (int p = 0; p < KH; ++p) lsum += lpart[(size_t)p * ROWS + arow];
    float linv = 1.f / lsum;
    for (int s = 0; s < 4; ++s) {
      const size_t base = (size_t)arow * DIM + s * 32 + quad * 8;   // us units
      float f[8] = {0.f, 0.f, 0.f, 0.f, 0.f, 0.f, 0.f, 0.f};
#pragma unroll
      for (int p = 0; p < KH; ++p) {
        US8 u = *reinterpret_cast<const US8*>(opart + (size_t)p * ROWS * DIM + base);
#pragma unroll
        for (int j = 0; j < 8; ++j)
          f[j] += __builtin_bit_cast(float, (unsigned)u.us[j] << 16);
      }
      US8 af;
#pragma unroll
      for (int j = 0; j < 8; ++j) af.us[j] = f2bf(f[j] * linv);
      bf16x8 a = __builtin_bit_cast(bf16x8, af);
      for (int g = 0; g < 8; ++g) {
        bf16x8 bfr = *reinterpret_cast<const bf16x8*>(&WT[(g * 16 + l16) * 136 + s * 32 + quad * 8]);
        acc[g] = __builtin_amdgcn_mfma_f32_16x16x32_bf16(a, bfr, acc[g], 0, 0, 0);
      }
    }
    for (int g = 0; g < 8; ++g) {
      float bias = bp[g * 16 + l16];
      for (int r = 0; r < 4; ++r) {
        int orow = row0c + wv * 16 + quad * 4 + r;
        out[(size_t)orow * DIM + g * 16 + l16] = acc[g][r] + bias;
      }
    }
  }
}

extern "C" void kernel_launch(void* const* d_in, const int* in_sizes, int n_in,
                              void* d_out, int out_size, void* d_ws, size_t ws_size,
                              hipStream_t stream) {
  (void)in_sizes; (void)n_in; (void)out_size; (void)ws_size;
  const float* x   = (const float*)d_in[0];
  const float* qg  = (const float*)d_in[1];
  const float* Wkv = (const float*)d_in[2];
  const float* bkv = (const float*)d_in[3];
  const float* Wp  = (const float*)d_in[4];
  const float* bp  = (const float*)d_in[5];
  float* out = (float*)d_out;

  // workspace: 3x bf16 bufs 25.2MB | l 512KB | O partials (bf16, KH=4) 33.6MB | cnt 4B
  unsigned short* qbf  = (unsigned short*)d_ws;
  unsigned short* kbf  = qbf + (size_t)ROWS * DIM;
  unsigned short* vtbf = kbf + (size_t)ROWS * DIM;
  float* lpart = (float*)(vtbf + (size_t)ROWS * DIM);
  unsigned short* opart = (unsigned short*)(lpart + (size_t)KH * ROWS);
  int* cnt = (int*)(opart + (size_t)KH * ROWS * DIM);

  hipLaunchKernelGGL(kvq_kernel, dim3(1024 + 2048), dim3(256), 0, stream,
                     x, Wkv, bkv, qg, kbf, vtbf, qbf, cnt);
  hipLaunchKernelGGL(attn_kernel, dim3(NBLK), dim3(256), 0, stream,
                     kbf, qbf, vtbf, opart, lpart, Wp, bp, out, cnt);
}

// Round 11
// 165.428 us; speedup vs baseline: 1.9095x; 1.9095x over previous
//
#include <hip/hip_runtime.h>

// ---------- types / helpers ----------
typedef __bf16 bf16x8 __attribute__((ext_vector_type(8)));
typedef float f32x4 __attribute__((ext_vector_type(4)));
typedef float f32x16 __attribute__((ext_vector_type(16)));

struct alignas(16) US8 { unsigned short us[8]; };

static __device__ inline unsigned short f2bf(float f) {
  union { float f; unsigned u; } v; v.f = f;
  unsigned r = v.u + 0x7fffu + ((v.u >> 16) & 1u);   // RNE
  return (unsigned short)(r >> 16);
}

static __device__ inline void gload16(const unsigned short* g, unsigned short* l) {
  // direct-to-LDS DMA, 16B/lane; LDS dest = wave-uniform base + lane*16
  __builtin_amdgcn_global_load_lds(
      (const __attribute__((address_space(1))) void*)g,
      (__attribute__((address_space(3))) void*)l, 16, 0, 0);
}

// B=8, N=4096, D=128.  32768 total rows.
#define NSEQ 4096
#define DIM 128
#define ROWS 32768
#define KH 4                      // cross-block key splits in attn (grid 512, 2 blocks/CU)

// log2(e)/sqrt(128): folded into q so S exits QK^T already in log2 domain
#define EXPC (1.4426950408889634f * 0.08838834764831845f)

// ---------- prep: weight transposes to bf16 (96 blocks, ~2 us, runs first) ----------
__global__ void prep_kernel(const float* __restrict__ Wkv, const float* __restrict__ Wp,
                            unsigned short* __restrict__ wkvT, unsigned short* __restrict__ wpT) {
  const int t = threadIdx.x;
  const int d = (t & 63) * 2;
  if (blockIdx.x < 64) {
    const int col = blockIdx.x * 4 + (t >> 6);
    unsigned short lo = f2bf(Wkv[d * 256 + col]);
    unsigned short hi = f2bf(Wkv[(d + 1) * 256 + col]);
    *reinterpret_cast<unsigned*>(&wkvT[col * 128 + d]) = (unsigned)lo | ((unsigned)hi << 16);
  } else {
    const int col = (blockIdx.x - 64) * 4 + (t >> 6);
    unsigned short lo = f2bf(Wp[d * 128 + col]);
    unsigned short hi = f2bf(Wp[(d + 1) * 128 + col]);
    *reinterpret_cast<unsigned*>(&wpT[col * 128 + d]) = (unsigned)lo | ((unsigned)hi << 16);
  }
}

// ---------- kv GEMM (blocks 0..1023) + qcast tail (blocks 1024..1535, grid-stride x4) ----------
// GEMM: COLUMN-SPLIT, 512 row-groups x 2 col-halves; weights LDS-staged (34.8 KB -> 4 blocks/CU).
// half 0 -> k (LDS restage, coalesced uint4 row-major stores);
// half 1 -> v (LDS transpose, blocked+permuted).
// Blocked V layout per batch: [tile(64 keys)][chunk 16][lane 64][8] where chunk=(mg,dh):
//   element (chunk, l, j) = V[m' = mg*8+j][d = dh*64+l], m' = key order with bit2<->bit3
//   swapped per 16-block (matches 32x32 MFMA C/D->A reg order in attn's PV).
// Blocked q_hat layout per batch: [tile(64 rows)][kc 16][lane 64][8]:
//   element = q_hat[row = tile*64+l][d = kc*8+j].
__global__ __launch_bounds__(256, 4) void kvq_kernel(
    const float* __restrict__ x, const unsigned short* __restrict__ wkvT,
    const float* __restrict__ bkv, const float* __restrict__ q,
    unsigned short* __restrict__ kout, unsigned short* __restrict__ vtout,
    unsigned short* __restrict__ qo) {
  const int tid = threadIdx.x;
  __shared__ __align__(16) unsigned short WT[128 * 136];   // [col][d] stride 136 (34.8 KB)
  if (blockIdx.x >= 1024) {                 // qcast tail, 512 blocks x 4 chunks each
    for (int itq = 0; itq < 4; ++itq) {
      int i = (((blockIdx.x - 1024) * 4 + itq) * 256 + tid) * 8;
      const float4* p = reinterpret_cast<const float4*>(q + i);
      float4 a = p[0], b = p[1];
      US8 o;
      o.us[0]=f2bf(a.x*EXPC); o.us[1]=f2bf(a.y*EXPC); o.us[2]=f2bf(a.z*EXPC); o.us[3]=f2bf(a.w*EXPC);
      o.us[4]=f2bf(b.x*EXPC); o.us[5]=f2bf(b.y*EXPC); o.us[6]=f2bf(b.z*EXPC); o.us[7]=f2bf(b.w*EXPC);
      int row = i >> 7, d0 = i & 127;
      int bb = row >> 12, n = row & (NSEQ - 1), tile = n >> 6, l = n & 63, kc = d0 >> 3;
      *reinterpret_cast<US8*>(qo + (size_t)bb * NSEQ * DIM + tile * 8192 + kc * 512 + l * 8) = o;
    }
    return;
  }
  const int wv = tid >> 6, lane = tid & 63, l16 = lane & 15, quad = lane >> 4;
  const int half = blockIdx.x & 1;
  const int row0 = (blockIdx.x >> 1) * 64;

  for (int p = 0; p < 8; ++p) {             // stage this col-half of wkvT (b128 both sides)
    int c = p * 256 + tid;
    int col = c >> 4, c16 = c & 15;
    *reinterpret_cast<US8*>(&WT[col * 136 + c16 * 8]) =
        *reinterpret_cast<const US8*>(wkvT + (half * 128 + col) * 128 + c16 * 8);
  }
  __syncthreads();

  bf16x8 afrag[4];
  const int arow = row0 + wv * 16 + l16;
  for (int s = 0; s < 4; ++s) {
    const float4* xp = reinterpret_cast<const float4*>(x + (size_t)arow * DIM + s * 32 + quad * 8);
    float4 u0 = xp[0], u1 = xp[1];
    US8 af;
    af.us[0]=f2bf(u0.x); af.us[1]=f2bf(u0.y); af.us[2]=f2bf(u0.z); af.us[3]=f2bf(u0.w);
    af.us[4]=f2bf(u1.x); af.us[5]=f2bf(u1.y); af.us[6]=f2bf(u1.z); af.us[7]=f2bf(u1.w);
    afrag[s] = __builtin_bit_cast(bf16x8, af);
  }
  f32x4 acc[8];
  for (int g = 0; g < 8; ++g) acc[g] = f32x4{0.f, 0.f, 0.f, 0.f};
  for (int s = 0; s < 4; ++s)
    for (int g = 0; g < 8; ++g) {
      bf16x8 bfr = *reinterpret_cast<const bf16x8*>(&WT[(g * 16 + l16) * 136 + s * 32 + quad * 8]);
      acc[g] = __builtin_amdgcn_mfma_f32_16x16x32_bf16(afrag[s], bfr, acc[g], 0, 0, 0);
    }

  __syncthreads();                          // all waves done reading weights from WT
  if (half == 0) {
    // k: stage rows into LDS [rowl][col] stride 136, then coalesced b128 row-major stores.
    // C/D: row=quad*4+r, col=l16
    for (int g = 0; g < 8; ++g) {
      float bias = bkv[g * 16 + l16];
      for (int r = 0; r < 4; ++r)
        WT[(wv * 16 + quad * 4 + r) * 136 + g * 16 + l16] = f2bf(acc[g][r] + bias);
    }
    __syncthreads();
    unsigned short* kbo = kout + (size_t)row0 * DIM;
    for (int p = 0; p < 4; ++p) {           // 1024 16B units: 64 rows x 16 segs
      int c = p * 256 + tid;
      int rowl = c >> 4, seg = c & 15;
      *reinterpret_cast<uint4*>(kbo + (size_t)rowl * DIM + seg * 8) =
          *reinterpret_cast<const uint4*>(&WT[rowl * 136 + seg * 8]);
    }
  } else {
    // v: transpose through LDS (stride 72), then blocked+permuted b128 global stores
    unsigned short* LDSt = WT;              // [d 128][n_local 64] stride 72 (reuses WT)
    for (int g = 0; g < 8; ++g) {
      float bias = bkv[128 + g * 16 + l16];
      for (int r = 0; r < 4; ++r)
        LDSt[(g * 16 + l16) * 72 + wv * 16 + quad * 4 + r] = f2bf(acc[g][r] + bias);
    }
    __syncthreads();
    const int bb = row0 >> 12;
    const int tile = (row0 & (NSEQ - 1)) >> 6;
    unsigned short* vbo = vtout + (size_t)bb * NSEQ * DIM + (size_t)tile * 8192;
    for (int p = 0; p < 4; ++p) {           // 1024 16B units: 16 chunks x 64 lanes
      int c = p * 256 + tid;
      int idx = c >> 6, l = c & 63;
      int mg = idx >> 1, dh = idx & 1, d = dh * 64 + l;
      int nb = (mg >> 1) * 16 + (mg & 1) * 4;   // first 4-run (bit2<->3 swap)
      uint2 lo = *reinterpret_cast<const uint2*>(&LDSt[d * 72 + nb]);
      uint2 hi = *reinterpret_cast<const uint2*>(&LDSt[d * 72 + nb + 8]);
      uint4 o{lo.x, lo.y, hi.x, hi.y};
      *reinterpret_cast<uint4*>(vbo + (size_t)idx * 512 + l * 8) = o;
    }
  }
}

// ---------- flash attention partials (32x32x16 MFMA, 64 n-rows/wave, 2-PASS QK) ----------
// grid 512 = 8 batches x 16 q-tiles (256 rows) x 4 key-splits; 2 blocks/CU, 64 KB LDS dbuf.
// Each wave owns TWO 32-row n-sets (kfrag[2][8]); PV amortizes every V read over 2 MFMAs.
// QK runs as TWO sequential ks-passes reusing ONE S register block (16 regs) so the
// VGPR-side peak is kfrag 64 + S 16 + pA/pB 16 + misc ~20 < 128 (split-K variant with
// Se/So both live spills -- measured r10: +20MB scratch writes, MfmaUtil 12%).
// O partials written bf16 (halves the opart HBM round-trip; ~4e-5 added out error).
__global__ __launch_bounds__(256, 2) void attn_kernel(
    const unsigned short* __restrict__ kbuf, const unsigned short* __restrict__ qblk,
    const unsigned short* __restrict__ vblk,
    unsigned short* __restrict__ opart, float* __restrict__ lpart) {
  __shared__ __align__(16) unsigned short SH[32768];   // 2 x (Qh 8192 | V 8192) = 64 KB
  const int tid = threadIdx.x;
  const int wv = tid >> 6, lane = tid & 63, l32 = lane & 31, h = lane >> 5;
  const int b = blockIdx.x & 7;
  const int t = blockIdx.x >> 3;
  const int q0 = (t & 15) * 256;
  const int kh = t >> 4;                    // 0..3
  const int key0 = kh * (NSEQ / KH);
  const unsigned short* kb = kbuf + (size_t)b * NSEQ * DIM;
  const unsigned short* qb = qblk + (size_t)b * NSEQ * DIM;
  const unsigned short* vb = vblk + (size_t)b * NSEQ * DIM;

  // staging: waves 0-1 stage the 16 q-hat chunks, waves 2-3 the 16 V chunks
  const unsigned short* sbase = ((wv < 2) ? qb : vb) + (size_t)(key0 >> 6) * 8192
                                + (wv & 1) * 4096 + lane * 8;
  const int ldst = (wv >> 1) * 8192 + (wv & 1) * 4096;   // us offset within a buffer

  constexpr int NT = NSEQ / KH / 64;        // 16

  // prologue: stage tile 0 into buffer 0 (overlaps kfrag loads)
#pragma unroll
  for (int c = 0; c < 8; ++c)
    gload16(sbase + c * 512, &SH[ldst + c * 512]);

  // B-operand frags: this wave's 64 n-rows of k (2 sets of 32). B[k=h*8+j][n=l32]
  bf16x8 kfrag[2][8];
#pragma unroll
  for (int nf = 0; nf < 2; ++nf)
#pragma unroll
    for (int ks = 0; ks < 8; ++ks)
      kfrag[nf][ks] = __builtin_bit_cast(bf16x8, *reinterpret_cast<const US8*>(
          kb + (size_t)(q0 + nf * 128 + wv * 32 + l32) * DIM + ks * 16 + h * 8));

  f32x16 Oacc[2][4];
#pragma unroll
  for (int nf = 0; nf < 2; ++nf)
    for (int dt = 0; dt < 4; ++dt)
      for (int i = 0; i < 16; ++i) Oacc[nf][dt][i] = 0.f;
  float lsum0 = 0.f, lsum1 = 0.f;

  __syncthreads();                          // tile 0 staged (vmcnt(0) + barrier)

  for (int it = 0; it < NT; ++it) {
    const int cur = (it & 1) << 14;         // 0 / 16384
    if (it + 1 < NT) {                      // issue next tile's DMA into other buffer
      const int nxt = cur ^ 16384;
      const unsigned short* sp = sbase + (size_t)(it + 1) * 8192;
#pragma unroll
      for (int c = 0; c < 8; ++c)
        gload16(sp + c * 512, &SH[nxt + ldst + c * 512]);
    }
    const unsigned short* Qsh = SH + cur;
    const unsigned short* Vsh = Qsh + 8192;

#pragma unroll
    for (int T = 0; T < 2; ++T) {
      bf16x8 pA[2], pB[2];
      // ---- QK pass 1 (n-set 0), S reused ----
      {
        f32x16 S;
        for (int i = 0; i < 16; ++i) S[i] = 0.f;
        __builtin_amdgcn_s_setprio(1);
#pragma unroll
        for (int ks = 0; ks < 8; ++ks) {
          bf16x8 a = *reinterpret_cast<const bf16x8*>(
              &Qsh[(ks * 2 + h) * 512 + (T * 32 + l32) * 8]);
          S = __builtin_amdgcn_mfma_f32_32x32x16_bf16(a, kfrag[0][ks], S, 0, 0, 0);
        }
        __builtin_amdgcn_s_setprio(0);
        unsigned pk[8];
#pragma unroll
        for (int i2 = 0; i2 < 8; ++i2) {
          float e0 = __builtin_amdgcn_exp2f(S[i2 * 2]);
          float e1 = __builtin_amdgcn_exp2f(S[i2 * 2 + 1]);
          lsum0 += e0; lsum0 += e1;
          pk[i2] = __builtin_amdgcn_perm(__builtin_bit_cast(unsigned, e1),
                                         __builtin_bit_cast(unsigned, e0), 0x07060302u);
        }
        pA[0] = __builtin_bit_cast(bf16x8, uint4{pk[0], pk[1], pk[2], pk[3]});
        pA[1] = __builtin_bit_cast(bf16x8, uint4{pk[4], pk[5], pk[6], pk[7]});
      }
      // ---- QK pass 2 (n-set 1), same q-hat chunks re-read ----
      {
        f32x16 S;
        for (int i = 0; i < 16; ++i) S[i] = 0.f;
        __builtin_amdgcn_s_setprio(1);
#pragma unroll
        for (int ks = 0; ks < 8; ++ks) {
          bf16x8 a = *reinterpret_cast<const bf16x8*>(
              &Qsh[(ks * 2 + h) * 512 + (T * 32 + l32) * 8]);
          S = __builtin_amdgcn_mfma_f32_32x32x16_bf16(a, kfrag[1][ks], S, 0, 0, 0);
        }
        __builtin_amdgcn_s_setprio(0);
        unsigned pk[8];
#pragma unroll
        for (int i2 = 0; i2 < 8; ++i2) {
          float e0 = __builtin_amdgcn_exp2f(S[i2 * 2]);
          float e1 = __builtin_amdgcn_exp2f(S[i2 * 2 + 1]);
          lsum1 += e0; lsum1 += e1;
          pk[i2] = __builtin_amdgcn_perm(__builtin_bit_cast(unsigned, e1),
                                         __builtin_bit_cast(unsigned, e0), 0x07060302u);
        }
        pB[0] = __builtin_bit_cast(bf16x8, uint4{pk[0], pk[1], pk[2], pk[3]});
        pB[1] = __builtin_bit_cast(bf16x8, uint4{pk[4], pk[5], pk[6], pk[7]});
      }
      // ---- PV for m-tile T: each V read feeds 2 MFMAs (both n-sets) ----
      __builtin_amdgcn_s_setprio(1);
#pragma unroll
      for (int s = 0; s < 2; ++s) {
        const int mg = 4 * T + 2 * s + h;
#pragma unroll
        for (int dt = 0; dt < 4; ++dt) {
          bf16x8 bv = *reinterpret_cast<const bf16x8*>(
              &Vsh[(mg * 2 + (dt >> 1)) * 512 + ((dt & 1) * 32 + l32) * 8]);
          Oacc[0][dt] = __builtin_amdgcn_mfma_f32_32x32x16_bf16(pA[s], bv, Oacc[0][dt], 0, 0, 0);
          Oacc[1][dt] = __builtin_amdgcn_mfma_f32_32x32x16_bf16(pB[s], bv, Oacc[1][dt], 0, 0, 0);
        }
      }
      __builtin_amdgcn_s_setprio(0);
    }

    __syncthreads();   // reads of buf[cur] done; next tile's DMA drained (vmcnt(0))
  }

  // l: per-lane covers its h-half of m for q-row n=l32 of each n-set; merge halves
  {
    float v0 = lsum0 + __shfl_xor(lsum0, 32);
    float v1 = lsum1 + __shfl_xor(lsum1, 32);
    if (lane < 32) {
      lpart[(size_t)kh * ROWS + (size_t)b * NSEQ + q0 + wv * 32 + l32] = v0;
      lpart[(size_t)kh * ROWS + (size_t)b * NSEQ + q0 + 128 + wv * 32 + l32] = v1;
    }
  }
#pragma unroll
  for (int nf = 0; nf < 2; ++nf) {
    unsigned short* ob = opart + (size_t)kh * ROWS * DIM
                         + ((size_t)b * NSEQ + q0 + nf * 128 + wv * 32) * DIM;
    for (int dt = 0; dt < 4; ++dt)
      for (int i = 0; i < 16; ++i) {
        int n = (i & 3) + 8 * (i >> 2) + 4 * h;   // 32x32 C/D row map (measured m74/m101)
        ob[n * DIM + dt * 32 + l32] = f2bf(Oacc[nf][dt][i]);
      }
  }
}

// ---------- combine bf16 partials (4 slices), normalize, out = o @ Wp + bp ----------
// 64 rows per block (512 blocks); wpT LDS-staged (34.8 KB -> 4 blocks/CU).
__global__ __launch_bounds__(256, 4) void combine_proj_kernel(
    const unsigned short* __restrict__ opart, const float* __restrict__ lpart,
    const unsigned short* __restrict__ wpT, const float* __restrict__ bp,
    float* __restrict__ out) {
  __shared__ __align__(16) unsigned short WT[128 * 136];
  const int tid = threadIdx.x;
  const int wv = tid >> 6, lane = tid & 63, l16 = lane & 15, quad = lane >> 4;
  const int row0 = blockIdx.x * 64;

  for (int p = 0; p < 8; ++p) {
    int c = p * 256 + tid;
    int col = c >> 4, c16 = c & 15;
    *reinterpret_cast<US8*>(&WT[col * 136 + c16 * 8]) =
        *reinterpret_cast<const US8*>(wpT + col * 128 + c16 * 8);
  }
  __syncthreads();

  f32x4 acc[8];
  for (int g = 0; g < 8; ++g) acc[g] = f32x4{0.f, 0.f, 0.f, 0.f};
  const int arow = row0 + wv * 16 + l16;
  float lsum = 0.f;
#pragma unroll
  for (int p = 0; p < KH; ++p) lsum += lpart[(size_t)p * ROWS + arow];
  float linv = 1.f / lsum;
  for (int s = 0; s < 4; ++s) {
    const size_t base = (size_t)arow * DIM + s * 32 + quad * 8;   // us units
    float f[8] = {0.f, 0.f, 0.f, 0.f, 0.f, 0.f, 0.f, 0.f};
#pragma unroll
    for (int p = 0; p < KH; ++p) {
      US8 u = *reinterpret_cast<const US8*>(opart + (size_t)p * ROWS * DIM + base);
#pragma unroll
      for (int j = 0; j < 8; ++j)
        f[j] += __builtin_bit_cast(float, (unsigned)u.us[j] << 16);
    }
    US8 af;
#pragma unroll
    for (int j = 0; j < 8; ++j) af.us[j] = f2bf(f[j] * linv);
    bf16x8 a = __builtin_bit_cast(bf16x8, af);
    for (int g = 0; g < 8; ++g) {
      bf16x8 bfr = *reinterpret_cast<const bf16x8*>(&WT[(g * 16 + l16) * 136 + s * 32 + quad * 8]);
      acc[g] = __builtin_amdgcn_mfma_f32_16x16x32_bf16(a, bfr, acc[g], 0, 0, 0);
    }
  }
  for (int g = 0; g < 8; ++g) {
    float bias = bp[g * 16 + l16];
    for (int r = 0; r < 4; ++r) {
      int orow = row0 + wv * 16 + quad * 4 + r;
      out[(size_t)orow * DIM + g * 16 + l16] = acc[g][r] + bias;
    }
  }
}

extern "C" void kernel_launch(void* const* d_in, const int* in_sizes, int n_in,
                              void* d_out, int out_size, void* d_ws, size_t ws_size,
                              hipStream_t stream) {
  (void)in_sizes; (void)n_in; (void)out_size; (void)ws_size;
  const float* x   = (const float*)d_in[0];
  const float* qg  = (const float*)d_in[1];
  const float* Wkv = (const float*)d_in[2];
  const float* bkv = (const float*)d_in[3];
  const float* Wp  = (const float*)d_in[4];
  const float* bp  = (const float*)d_in[5];
  float* out = (float*)d_out;

  // workspace: 3x bf16 bufs 25.2MB | weights 96KB | l 512KB | O partials (bf16, KH=4) 33.6MB
  unsigned short* qbf  = (unsigned short*)d_ws;
  unsigned short* kbf  = qbf + (size_t)ROWS * DIM;
  unsigned short* vtbf = kbf + (size_t)ROWS * DIM;
  unsigned short* wkvT = vtbf + (size_t)ROWS * DIM;
  unsigned short* wpT  = wkvT + 256 * 128;
  float* lpart = (float*)(wpT + 128 * 128);
  unsigned short* opart = (unsigned short*)(lpart + (size_t)KH * ROWS);

  hipLaunchKernelGGL(prep_kernel, dim3(96), dim3(256), 0, stream, Wkv, Wp, wkvT, wpT);
  hipLaunchKernelGGL(kvq_kernel, dim3(1024 + 512), dim3(256), 0, stream,
                     x, wkvT, bkv, qg, kbf, vtbf, qbf);
  hipLaunchKernelGGL(attn_kernel, dim3(8 * 16 * KH), dim3(256), 0, stream, kbf, qbf, vtbf, opart, lpart);
  hipLaunchKernelGGL(combine_proj_kernel, dim3(ROWS / 64), dim3(256), 0, stream, opart, lpart, wpT, bp, out);
}